// Round 2
// baseline (825.400 us; speedup 1.0000x reference)
//
#include <hip/hip_runtime.h>
#include <cstdint>

#define T_DIM 2048
#define B_DIM 16
#define D_DIM 1024
#define M_DIM (T_DIM * B_DIM)        // 32768 rows
#define BD (B_DIM * D_DIM)           // 16384 independent scan states
#define CCH 64                       // scan chunks
#define LCH (T_DIM / CCH)            // 32 steps per chunk

typedef _Float16 f16x8 __attribute__((ext_vector_type(8)));
typedef float f32x4 __attribute__((ext_vector_type(4)));

// async global -> LDS, 16B per lane. LDS dest must be wave-uniform base +
// lane*16 within each wave (tid*16 satisfies this per 64-lane wave).
__device__ __forceinline__ void async_cp16(const void* g, void* l) {
  __builtin_amdgcn_global_load_lds(
      (const __attribute__((address_space(1))) void*)(uintptr_t)g,
      (__attribute__((address_space(3))) void*)(uint32_t)(uintptr_t)l,
      16, 0, 0);
}

__device__ __forceinline__ float sigmoidf_(float z) {
  return 1.f / (1.f + __expf(-z));
}
__device__ __forceinline__ float tanhf_(float z) {
  float t = __expf(2.f * z);          // |z| <= ~8 here; no overflow
  return (t - 1.f) / (t + 1.f);
}

// ---------------- f32 -> f16 convert, 8 elems/thread ----------------
__global__ void cvt_f32_f16(const float* __restrict__ s, _Float16* __restrict__ d, int n8) {
  int i = blockIdx.x * blockDim.x + threadIdx.x;
  if (i >= n8) return;
  const float4* sp = (const float4*)s;
  float4 u = sp[2 * i];
  float4 v = sp[2 * i + 1];
  f16x8 o;
  o[0] = (_Float16)u.x; o[1] = (_Float16)u.y; o[2] = (_Float16)u.z; o[3] = (_Float16)u.w;
  o[4] = (_Float16)v.x; o[5] = (_Float16)v.y; o[6] = (_Float16)v.z; o[7] = (_Float16)v.w;
  *(f16x8*)(d + (size_t)i * 8) = o;
}

// ---------------- fused 3-gate GEMM + gate combine ----------------
// z_w[m][e] = sum_d x[m][d] * W_w[e][d]; writes retain -> Aret, write -> Bwr.
// Tile 128x128, BK=32, 8 waves (2x4), wave tile 64x32, mfma 16x16x32 f16.
__global__ __launch_bounds__(512, 2) void gate_gemm(
    const _Float16* __restrict__ x16,
    const _Float16* __restrict__ wa16,
    const _Float16* __restrict__ wk16,
    const _Float16* __restrict__ wv16,
    const float* __restrict__ ba, const float* __restrict__ bk, const float* __restrict__ bv,
    float* __restrict__ Aret, float* __restrict__ Bwr) {
  __shared__ __align__(16) _Float16 sA[2][128][32];      // 16 KiB
  __shared__ __align__(16) _Float16 sB[2][3][128][32];   // 48 KiB

  const int tid  = threadIdx.x;
  const int wid  = tid >> 6;
  const int lane = tid & 63;
  const int wm = wid >> 2;    // 0..1 : 64-row slab
  const int wn = wid & 3;     // 0..3 : 32-col slab
  const int lr = lane & 15;
  const int kg = lane >> 4;

  const int m0 = blockIdx.x * 128;
  const int n0 = blockIdx.y * 128;

  const int arow = tid >> 2;  // 0..127
  const int achk = tid & 3;   // 0..3 (16B chunk within 64B row)

  f32x4 acc[3][4][2];
#pragma unroll
  for (int w = 0; w < 3; ++w)
#pragma unroll
    for (int mi = 0; mi < 4; ++mi)
#pragma unroll
      for (int ni = 0; ni < 2; ++ni)
        acc[w][mi][ni] = (f32x4)0.f;

  const size_t gA0 = (size_t)(m0 + arow) * D_DIM + achk * 8;
  const size_t gB0 = (size_t)(n0 + arow) * D_DIM + achk * 8;

  auto stage = [&](int buf, int kk) {
    async_cp16(x16  + gA0 + kk * 32, (char*)&sA[buf][0][0]    + tid * 16);
    async_cp16(wa16 + gB0 + kk * 32, (char*)&sB[buf][0][0][0] + tid * 16);
    async_cp16(wk16 + gB0 + kk * 32, (char*)&sB[buf][1][0][0] + tid * 16);
    async_cp16(wv16 + gB0 + kk * 32, (char*)&sB[buf][2][0][0] + tid * 16);
  };

  auto compute = [&](int buf) {
    f16x8 af[4];
#pragma unroll
    for (int mi = 0; mi < 4; ++mi)
      af[mi] = *(const f16x8*)&sA[buf][wm * 64 + mi * 16 + lr][kg * 8];
#pragma unroll
    for (int w = 0; w < 3; ++w) {
      f16x8 b0 = *(const f16x8*)&sB[buf][w][wn * 32 + lr][kg * 8];
      f16x8 b1 = *(const f16x8*)&sB[buf][w][wn * 32 + 16 + lr][kg * 8];
#pragma unroll
      for (int mi = 0; mi < 4; ++mi) {
        acc[w][mi][0] = __builtin_amdgcn_mfma_f32_16x16x32_f16(af[mi], b0, acc[w][mi][0], 0, 0, 0);
        acc[w][mi][1] = __builtin_amdgcn_mfma_f32_16x16x32_f16(af[mi], b1, acc[w][mi][1], 0, 0, 0);
      }
    }
  };

  stage(0, 0);
  __syncthreads();
  int cur = 0;
#pragma unroll 1
  for (int kk = 0; kk < 32; ++kk) {
    if (kk + 1 < 32) stage(cur ^ 1, kk + 1);  // next-tile loads fly under MFMA
    compute(cur);
    __syncthreads();                           // drains vmcnt+lgkmcnt
    cur ^= 1;
  }

  // epilogue: gates + combine, direct store (no z round-trip)
  // C/D mapping (m89-verified): col = lane&15, row = (lane>>4)*4 + reg
#pragma unroll
  for (int ni = 0; ni < 2; ++ni) {
    const int e = n0 + wn * 32 + ni * 16 + lr;
    const float ba_ = ba[e], bk_ = bk[e], bv_ = bv[e];
#pragma unroll
    for (int mi = 0; mi < 4; ++mi) {
      const int mbase = m0 + wm * 64 + mi * 16 + kg * 4;
#pragma unroll
      for (int r = 0; r < 4; ++r) {
        const size_t m = (size_t)(mbase + r);
        float al  = sigmoidf_(acc[0][mi][ni][r] + ba_);
        float kk_ = sigmoidf_(acc[1][mi][ni][r] + bk_);
        float vv  = tanhf_(acc[2][mi][ni][r] + bv_);
        Aret[m * D_DIM + e] = al * (1.f - kk_);
        Bwr [m * D_DIM + e] = kk_ * vv;
      }
    }
  }
}

// ---------------- scan phase 1: per-chunk affine composition ----------------
// (A,Bw) alias d_out regions but are read-only here; cP/cS live in ws.
__global__ void scan_phase1(const float* __restrict__ A, const float* __restrict__ Bw,
                            float* __restrict__ cP, float* __restrict__ cS) {
  int tid = blockIdx.x * 256 + threadIdx.x;       // c*BD + bd
  int bd = tid & (BD - 1);
  int c  = tid >> 14;
  size_t base = (size_t)c * LCH * BD + bd;
  float P = 1.f, S = 0.f;
#pragma unroll 4
  for (int t = 0; t < LCH; ++t) {
    float a = A[base + (size_t)t * BD];
    float b = Bw[base + (size_t)t * BD];
    S = fmaf(a, S, b);
    P *= a;
  }
  cP[tid] = P;
  cS[tid] = S;
}

// ---------------- scan phase 2: scan 64 chunk summaries per state ----------------
__global__ void scan_phase2(const float* __restrict__ h0,
                            const float* __restrict__ cP, const float* __restrict__ cS,
                            float* __restrict__ hst, float* __restrict__ hout) {
  int bd = blockIdx.x * 256 + threadIdx.x;        // 0..BD-1
  float h = h0[bd];
  hout[bd] = h;                                    // h[0] = h0 (outside Bwr region)
#pragma unroll 1
  for (int c = 0; c < CCH; ++c) {
    hst[(size_t)c * BD + bd] = h;
    h = fmaf(cP[(size_t)c * BD + bd], h, cS[(size_t)c * BD + bd]);
  }
}

// ---------------- scan phase 3: replay chunks, write h and output ----------------
// a lives at out[off] (Aret), b at hout[off+BD] (Bwr). Each thread reads its
// element then overwrites the same address -> no restrict, no race.
__global__ void scan_phase3(const float* __restrict__ hst,
                            float* out, float* hout) {
  int tid = blockIdx.x * 256 + threadIdx.x;
  int bd = tid & (BD - 1);
  int c  = tid >> 14;
  size_t base = (size_t)c * LCH * BD + bd;
  float h = hst[(size_t)c * BD + bd];
#pragma unroll 4
  for (int t = 0; t < LCH; ++t) {
    size_t off = base + (size_t)t * BD;
    float a = out[off];            // Aret
    float b = hout[off + BD];      // Bwr
    h = fmaf(a, h, b);
    hout[off + BD] = h;            // h[(c*LCH+t)+1]
    float sg = 1.f / (1.f + __expf(-h));
    out[off] = h * h * sg;         // hs^2 * sigmoid(hs)
  }
}

extern "C" void kernel_launch(void* const* d_in, const int* in_sizes, int n_in,
                              void* d_out, int out_size, void* d_ws, size_t ws_size,
                              hipStream_t stream) {
  const float* x  = (const float*)d_in[0];
  const float* h0 = (const float*)d_in[1];
  const float* Wa = (const float*)d_in[2];
  const float* ba = (const float*)d_in[3];
  const float* Wk = (const float*)d_in[4];
  const float* bk = (const float*)d_in[5];
  const float* Wv = (const float*)d_in[6];
  const float* bv = (const float*)d_in[7];

  float* out  = (float*)d_out;                       // [T,B,D]
  float* hout = out + (size_t)M_DIM * D_DIM;         // [T+1,B,D]

  // Big intermediates alias d_out (overwritten in place by scan_phase3):
  float* Aret = out;              // retain a_t  -> out region
  float* Bwr  = hout + BD;        // write  b_t  -> hout[1:] region

  // workspace (~70 MiB):
  //   [0,64Mi)    x16 (fp16 x)   -- region reused by cP/cS/hst after the GEMM
  //   [64Mi,70Mi) wa16/wk16/wv16
  char* ws = (char*)d_ws;
  _Float16* x16  = (_Float16*)ws;
  _Float16* wa16 = (_Float16*)(ws + 67108864);
  _Float16* wk16 = (_Float16*)(ws + 67108864 + 2097152);
  _Float16* wv16 = (_Float16*)(ws + 67108864 + 2 * 2097152);
  float* cP   = (float*)ws;                 // x16 dead after gate_gemm
  float* cS   = cP + (size_t)CCH * BD;      // +4 MiB
  float* hst  = cS + (size_t)CCH * BD;      // +4 MiB (4 MiB used)

  const int nx8 = M_DIM * D_DIM / 8;        // 4,194,304
  const int nw8 = D_DIM * D_DIM / 8;        // 131,072
  cvt_f32_f16<<<dim3((nx8 + 255) / 256), dim3(256), 0, stream>>>(x, x16, nx8);
  cvt_f32_f16<<<dim3((nw8 + 255) / 256), dim3(256), 0, stream>>>(Wa, wa16, nw8);
  cvt_f32_f16<<<dim3((nw8 + 255) / 256), dim3(256), 0, stream>>>(Wk, wk16, nw8);
  cvt_f32_f16<<<dim3((nw8 + 255) / 256), dim3(256), 0, stream>>>(Wv, wv16, nw8);

  gate_gemm<<<dim3(M_DIM / 128, D_DIM / 128), dim3(512), 0, stream>>>(
      x16, wa16, wk16, wv16, ba, bk, bv, Aret, Bwr);

  scan_phase1<<<dim3(CCH * BD / 256), dim3(256), 0, stream>>>(Aret, Bwr, cP, cS);
  scan_phase2<<<dim3(BD / 256), dim3(256), 0, stream>>>(h0, cP, cS, hst, hout);
  scan_phase3<<<dim3(CCH * BD / 256), dim3(256), 0, stream>>>(hst, out, hout);
}